// Round 2
// baseline (798.407 us; speedup 1.0000x reference)
//
#include <hip/hip_runtime.h>

// BuildCost: light-field cost volume
//   x:    [1, 32, 81, 192, 192] fp32
//   mask: [1, 81, 192, 192]     fp32
//   W:    [128, 81]             fp32   (grouped 1x1, groups=32, m=4 per group)
//   out:  [1, 128, 9, 192, 192] fp32
//
// out[c*4+m, d+4, i, j] = (81/sum_t mask[t,i,j]) *
//     sum_{p,q} x[c, p*9+q, i+(4-p)*d, j+(4-q)*d] * mask[p*9+q, i, j] * W[c*4+m, p*9+q]
// with out-of-bounds x reads = 0 (zero padding).
//
// v3: global_load_lds ring pipeline. v2 (register staging + __syncthreads)
// drained vmcnt to 0 every tap -> cold-HBM latency exposed 81x per block
// (377 us vs ~91 us memory roofline). Now:
//   - 4-buffer LDS ring, taps t+1..t+3 in flight via global_load_lds (16B),
//     no ds_write, no register staging.
//   - raw s_barrier + per-wave counted s_waitcnt vmcnt(2g) (never 0 in loop);
//     g = wave's own per-tap VMEM count (computed via __any for border waves
//     whose guarded loads may be entirely exec-masked off).
//   - tail issues are clamped to tap 80 (land in dead ring slots) so per-tap
//     issue counts are loop-invariant -> vmcnt literals stay valid.
//   - border OOB LDS slots zeroed ONCE (tap-invariant, exec-masked loads
//     never touch them).
//   - mask: 3-deep register rotation, unconditional clamped loads (compiler
//     emits counted waits, not vmcnt(0)).
//   - mval folded into w4 once per tap: 4 mul + 36 FMA per tap (was 45 ops).

#define AA   81
#define HH   192
#define WW   192
#define HW   (HH * WW)
#define NC   32
#define MM   4
#define ND   9

#define RG      48                 // staged region: 16 + 2*16 halo
#define RITEMS  (RG * RG / 4)      // 576 float4 items per tap
#define RING    4

__device__ __forceinline__ void glds16(const float* g, float4* l) {
    __builtin_amdgcn_global_load_lds(
        (const __attribute__((address_space(1))) void*)g,
        (__attribute__((address_space(3))) void*)l, 16, 0, 0);
}

__global__ __launch_bounds__(256)
void buildcost_kernel(const float* __restrict__ x,
                      const float* __restrict__ mask,
                      const float* __restrict__ Wt,
                      float* __restrict__ out) {
    __shared__ float  wlds[AA * MM];
    __shared__ float4 buf[RING][RITEMS];   // 4-deep ring of 48x48 fp32 regions

    const int lin  = blockIdx.x;
    const int xcd  = lin & 7;
    const int slot = lin >> 3;          // [0, 576)
    const int cgrp = slot / 144;        // [0, 4)
    const int sp   = slot - cgrp * 144; // [0, 144)
    const int c    = xcd + (cgrp << 3);
    const int by   = sp / 12;
    const int bx   = sp - by * 12;

    const int tid  = threadIdx.x;
    const int wave = tid >> 6;
    const int tx   = tid & 15;
    const int ty   = tid >> 4;
    const int j    = bx * 16 + tx;
    const int i    = by * 16 + ty;
    const int pix  = i * WW + j;

    // Stage weights transposed: wlds[t*4+m] = W[(c*4+m)*81 + t]
    for (int idx = tid; idx < AA * MM; idx += 256) {
        const int t = idx >> 2;
        const int m = idx & 3;
        wlds[idx] = Wt[(c * MM + m) * AA + t];
    }

    // ---- per-thread staged-item precompute (tap-independent) ----
    // item k covers region floats [k*4, k*4+4): row = k/12, col = (k%12)*4.
    // Region origin: (by*16-16, bx*16-16). Columns are 16B-aligned.
    const int y0 = by * 16 - 16;
    const int x0 = bx * 16 - 16;

    int off0, off1, off2;
    bool v0, v1, v2;
    {
        const int i0 = tid,        r0 = i0 / 12, c0 = (i0 - r0 * 12) * 4;
        const int i1 = tid + 256,  r1 = i1 / 12, c1 = (i1 - r1 * 12) * 4;
        const int i2 = tid + 512,  r2 = i2 / 12, c2 = (i2 - r2 * 12) * 4;
        const int gy0 = y0 + r0, gx0 = x0 + c0;
        const int gy1 = y0 + r1, gx1 = x0 + c1;
        const int gy2 = y0 + r2, gx2 = x0 + c2;
        v0 = ((unsigned)gy0 < (unsigned)HH) & ((unsigned)gx0 < (unsigned)WW);
        v1 = ((unsigned)gy1 < (unsigned)HH) & ((unsigned)gx1 < (unsigned)WW);
        v2 = ((unsigned)gy2 < (unsigned)HH) & ((unsigned)gx2 < (unsigned)WW);
        off0 = gy0 * WW + gx0;
        off1 = gy1 * WW + gx1;
        off2 = gy2 * WW + gx2;
    }
    const bool interior = (bx >= 1) & (bx <= 10) & (by >= 1) & (by <= 10);

    // Zero OOB slots once: exec-masked loads never write them, and the v-flags
    // are tap-invariant, so a slot that is OOB stays zero for all 81 taps.
    if (!interior) {
        const float4 z = {0.f, 0.f, 0.f, 0.f};
        if (!v0) { for (int r = 0; r < RING; ++r) buf[r][tid] = z; }
        if (!v1) { for (int r = 0; r < RING; ++r) buf[r][tid + 256] = z; }
        if (tid < 64 && !v2) { for (int r = 0; r < RING; ++r) buf[r][tid + 512] = z; }
    }
    asm volatile("s_waitcnt lgkmcnt(0)" ::: "memory");

    // Per-wave VMEM issue count per tap: guarded glds only issue if any lane
    // in the wave is valid. +1 for the mask register load.
    int gw = 1 + (__any((int)v0) ? 1 : 0) + (__any((int)v1) ? 1 : 0);
    if (wave == 0) gw += (__any((int)v2) ? 1 : 0);
    const int W2 = 2 * gw;   // steady-state wait: 2 groups in flight

    const float* __restrict__ xc = x + (size_t)c * AA * HW;

    // ---- prologue: issue taps 0..2, prefetch mask 0..2 into registers ----
    {
        const float* xt = xc;
#pragma unroll
        for (int tt = 0; tt < 3; ++tt) {
            float4* dst = &buf[tt][0];
            if (interior) {
                glds16(xt + off0, dst + (wave << 6));
                glds16(xt + off1, dst + 256 + (wave << 6));
                if (wave == 0) glds16(xt + off2, dst + 512);
            } else {
                if (v0) glds16(xt + off0, dst + (wave << 6));
                if (v1) glds16(xt + off1, dst + 256 + (wave << 6));
                if (wave == 0) { if (v2) glds16(xt + off2, dst + 512); }
            }
            xt += HW;
        }
    }
    float mv0 = mask[pix];
    float mv1 = mask[HW + pix];
    float mv2 = mask[2 * HW + pix];

    float acc[ND][MM];
#pragma unroll
    for (int dd = 0; dd < ND; ++dd)
#pragma unroll
        for (int m = 0; m < MM; ++m) acc[dd][m] = 0.f;

    const int lbase = (ty + 16) * RG + (tx + 16);
    float msum = 0.f;
    int p = 0, q = 0;

#pragma unroll 1
    for (int t = 0; t < AA; ++t) {
        // drain my own tap-t group (t==0: prologue issue order is unknown to
        // us, drain fully once), then barrier -> everyone's tap-t data in LDS
        if (t == 0) {
            asm volatile("s_waitcnt vmcnt(0)" ::: "memory");
        } else if (W2 == 8) {
            asm volatile("s_waitcnt vmcnt(8)" ::: "memory");
        } else if (W2 == 6) {
            asm volatile("s_waitcnt vmcnt(6)" ::: "memory");
        } else if (W2 == 4) {
            asm volatile("s_waitcnt vmcnt(4)" ::: "memory");
        } else {
            asm volatile("s_waitcnt vmcnt(2)" ::: "memory");
        }
        __builtin_amdgcn_s_barrier();

        const float mval = mv0;
        mv0 = mv1; mv1 = mv2;
        msum += mval;

        const float4 w4 = *(const float4*)&wlds[t * 4];
        const float wx = w4.x * mval;
        const float wy = w4.y * mval;
        const float wz = w4.z * mval;
        const float ww = w4.w * mval;

        const int kp = 4 - p;
        const int kq = 4 - q;
        const int lstep = kp * RG + kq;      // LDS word delta per +1 in d
        const float* lb = (const float*)&buf[t & (RING - 1)][0];

#pragma unroll
        for (int dd = 0; dd < ND; ++dd) {
            const float v = lb[lbase + (dd - 4) * lstep];
            acc[dd][0] += v * wx;
            acc[dd][1] += v * wy;
            acc[dd][2] += v * wz;
            acc[dd][3] += v * ww;
        }

        // issue tap t+3 (clamped to 80 in the tail so per-tap VMEM counts are
        // loop-invariant; clamped issues land in ring slots already consumed)
        const int tn = (t + 3 > 80) ? 80 : (t + 3);
        const float* xt3 = xc + (size_t)tn * HW;
        float4* dst = &buf[(t + 3) & (RING - 1)][0];
        if (interior) {
            glds16(xt3 + off0, dst + (wave << 6));
            glds16(xt3 + off1, dst + 256 + (wave << 6));
            if (wave == 0) glds16(xt3 + off2, dst + 512);
        } else {
            if (v0) glds16(xt3 + off0, dst + (wave << 6));
            if (v1) glds16(xt3 + off1, dst + 256 + (wave << 6));
            if (wave == 0) { if (v2) glds16(xt3 + off2, dst + 512); }
        }
        mv2 = mask[(size_t)tn * HW + pix];

        if (++q == 9) { q = 0; ++p; }
    }

    const float inv = (float)AA / msum;

#pragma unroll
    for (int m = 0; m < MM; ++m)
#pragma unroll
        for (int dd = 0; dd < ND; ++dd)
            out[((size_t)(c * MM + m) * ND + dd) * HW + pix] = acc[dd][m] * inv;
}

extern "C" void kernel_launch(void* const* d_in, const int* in_sizes, int n_in,
                              void* d_out, int out_size, void* d_ws, size_t ws_size,
                              hipStream_t stream) {
    const float* x    = (const float*)d_in[0];
    const float* mask = (const float*)d_in[1];
    const float* Wt   = (const float*)d_in[2];
    float* out        = (float*)d_out;

    dim3 grid(12 * 12 * NC);
    dim3 block(256);
    buildcost_kernel<<<grid, block, 0, stream>>>(x, mask, Wt, out);
}